// Round 9
// baseline (341.256 us; speedup 1.0000x reference)
//
#include <hip/hip_runtime.h>
#include <hip/hip_bf16.h>

// Problem constants (from reference)
#define NN      50000
#define EE      800000
#define EP      (EE + NN)      // edges + self loops
#define F_IN    128
#define HID     64
#define HEADS   4
#define NCLS    40
#define SLOPE   0.2f

#define NB_SCAN ((NN + 1023) / 1024)   // 49 blocks of 1024 elements

typedef _Float16 half8v __attribute__((ext_vector_type(8)));
typedef _Float16 half4v __attribute__((ext_vector_type(4)));
typedef _Float16 half2v __attribute__((ext_vector_type(2)));
typedef float    f32x4  __attribute__((ext_vector_type(4)));

__device__ __forceinline__ float lrelu_exp(float e) {
    e = (e > 0.f) ? e : SLOPE * e;
    return __expf(e);
}

// ---------------- CSR build ----------------

__global__ __launch_bounds__(256) void init_deg(int* deg) {
    int i = blockIdx.x * 256 + threadIdx.x;
    if (i < NN) deg[i] = 1;   // self-loop
}

__global__ __launch_bounds__(256) void hist_kernel(const int* __restrict__ ei, int* deg) {
    int e = blockIdx.x * 256 + threadIdx.x;
    if (e < EE) atomicAdd(&deg[ei[EE + e]], 1);   // dst = ei[1][e]
}

// ---- multi-block exclusive scan over NN degrees (3 passes, all parallel) ----
__global__ __launch_bounds__(256) void scan_blocks(const int* __restrict__ deg,
                                                   int* __restrict__ off,
                                                   int* __restrict__ bsum) {
    __shared__ int wsum[4];
    const int bid = blockIdx.x, t = threadIdx.x;
    const int base = bid * 1024 + t * 4;
    int d0 = 0, d1 = 0, d2 = 0, d3 = 0;
    if (base + 3 < NN) {
        int4 v = *(const int4*)(deg + base);
        d0 = v.x; d1 = v.y; d2 = v.z; d3 = v.w;
    } else {
        if (base + 0 < NN) d0 = deg[base + 0];
        if (base + 1 < NN) d1 = deg[base + 1];
        if (base + 2 < NN) d2 = deg[base + 2];
        if (base + 3 < NN) d3 = deg[base + 3];
    }
    const int tsum = d0 + d1 + d2 + d3;
    const int lane = t & 63, wv = t >> 6;
    int inc = tsum;
#pragma unroll
    for (int o = 1; o < 64; o <<= 1) {
        int u = __shfl_up(inc, o);
        if (lane >= o) inc += u;
    }
    if (lane == 63) wsum[wv] = inc;
    __syncthreads();
    int woff = 0;
#pragma unroll
    for (int w = 0; w < 4; ++w) woff += (w < wv) ? wsum[w] : 0;
    const int excl = woff + inc - tsum;
    if (base + 3 < NN) {
        int4 o4;
        o4.x = excl;
        o4.y = excl + d0;
        o4.z = excl + d0 + d1;
        o4.w = excl + d0 + d1 + d2;
        *(int4*)(off + base) = o4;
    } else {
        if (base + 0 < NN) off[base + 0] = excl;
        if (base + 1 < NN) off[base + 1] = excl + d0;
        if (base + 2 < NN) off[base + 2] = excl + d0 + d1;
        if (base + 3 < NN) off[base + 3] = excl + d0 + d1 + d2;
    }
    if (t == 255) bsum[bid] = woff + inc;   // block total
}

__global__ __launch_bounds__(64) void scan_spine(int* __restrict__ bsum,
                                                 int* __restrict__ off) {
    const int lane = threadIdx.x;
    int v = (lane < NB_SCAN) ? bsum[lane] : 0;
    int inc = v;
#pragma unroll
    for (int o = 1; o < 64; o <<= 1) {
        int u = __shfl_up(inc, o);
        if (lane >= o) inc += u;
    }
    if (lane < NB_SCAN) bsum[lane] = inc - v;   // exclusive prefix
    if (lane == 63) off[NN] = inc;              // grand total == EP
}

__global__ __launch_bounds__(256) void scan_apply(const int* __restrict__ bsum,
                                                  int* __restrict__ off,
                                                  int* __restrict__ cur) {
    const int bid = blockIdx.x, t = threadIdx.x;
    const int boff = bsum[bid];
    const int base = bid * 1024 + t * 4;
    if (base + 3 < NN) {
        int4 v = *(const int4*)(off + base);
        v.x += boff; v.y += boff; v.z += boff; v.w += boff;
        *(int4*)(off + base) = v;
        *(int4*)(cur + base) = v;
    } else {
        for (int i = 0; i < 4; ++i)
            if (base + i < NN) {
                int v = off[base + i] + boff;
                off[base + i] = v;
                cur[base + i] = v;
            }
    }
}

__global__ __launch_bounds__(256) void scatter_kernel(const int* __restrict__ ei,
                                                      int* __restrict__ cur,
                                                      int* __restrict__ csr) {
    int i = blockIdx.x * 256 + threadIdx.x;
    if (i >= EP) return;
    int s, d;
    if (i < NN) { s = i; d = i; }           // self loop
    else { int e = i - NN; s = ei[e]; d = ei[EE + e]; }
    int pos = atomicAdd(&cur[d], 1);
    csr[pos] = s;
}

// ---------------- W1 -> fragment-packed fp16 table (once per launch) ----------------
// Our chosen K-order sigma(g,j) = 8g + j applied identically to A and B fragments:
// GEMM result is invariant to any consistent K permutation, so the HW's internal
// per-lane k-map need not be known. Layout:
//   W1p[((f*4 + kk)*64 + l)*8 + j] = fp16( W1[32*kk + 8*(l>>4) + j][16*f + (l&15)] )
__global__ __launch_bounds__(256) void prep_w1(const float* __restrict__ W1,
                                               _Float16* __restrict__ W1p) {
    int idx = blockIdx.x * 256 + threadIdx.x;   // 16*4*64 = 4096 fragments-of-8
    if (idx >= 16 * 4 * 64) return;
    int l = idx & 63, kk = (idx >> 6) & 3, f = idx >> 8;
    int k0 = 32 * kk + 8 * (l >> 4);
    int c  = 16 * f + (l & 15);
    half8v v;
#pragma unroll
    for (int j = 0; j < 8; ++j) v[j] = (_Float16)W1[(size_t)(k0 + j) * 256 + c];
    *(half8v*)(W1p + (size_t)idx * 8) = v;
}

// ---------------- layer-1 GEMM via f16 MFMA ----------------
// C[M,256] = A[M,128] @ W1[128,256], f32 accumulate, fp16 output table.
// Block: 256 thr = 4 waves; BM=128 (wave w: rows 32w..32w+31, 2 M-frags).
// A staged f32->fp16 in LDS (row-major, XOR-swizzled); B-frags read from L2-hot W1p.
__global__ __launch_bounds__(256)
void gemm1_mfma(const float* __restrict__ A, const _Float16* __restrict__ W1p,
                _Float16* __restrict__ h1h, int M) {
    __shared__ _Float16 Al[128 * 128];   // 32 KB
    const int t    = threadIdx.x;
    const int row0 = blockIdx.x * 128;

    // stage A: 128x128 f32 -> fp16, coalesced reads, swizzled LDS writes
#pragma unroll
    for (int i = 0; i < 16; ++i) {
        int flat = i * 1024 + t * 4;      // element index in 128x128
        int r = flat >> 7, c = flat & 127;
        int rg = row0 + r; if (rg >= M) rg = M - 1;
        float4 v = *(const float4*)(A + (size_t)rg * 128 + c);
        half4v hv;
        hv.x = (_Float16)v.x; hv.y = (_Float16)v.y;
        hv.z = (_Float16)v.z; hv.w = (_Float16)v.w;
        int byte = (r * 256 + c * 2) ^ ((r & 7) << 4);
        *(half4v*)((char*)Al + byte) = hv;
    }
    __syncthreads();

    const int lane = t & 63;
    const int w    = t >> 6;
    const int g    = lane >> 4, cc = lane & 15;

    // A fragments: lane holds rows (l&15), k = 32kk + 8g + j (our sigma)
    half8v a[2][4];
#pragma unroll
    for (int m = 0; m < 2; ++m)
#pragma unroll
        for (int kk = 0; kk < 4; ++kk) {
            int r = 32 * w + 16 * m + cc;
            int byte = (r * 256 + (32 * kk + 8 * g) * 2) ^ ((r & 7) << 4);
            a[m][kk] = *(const half8v*)((const char*)Al + byte);
        }

    f32x4 acc[16][2];
#pragma unroll
    for (int n = 0; n < 16; ++n)
#pragma unroll
        for (int m = 0; m < 2; ++m)
#pragma unroll
            for (int i = 0; i < 4; ++i) acc[n][m][i] = 0.f;

#pragma unroll
    for (int n = 0; n < 16; ++n) {
        half8v b[4];
#pragma unroll
        for (int kk = 0; kk < 4; ++kk)
            b[kk] = *(const half8v*)(W1p + ((size_t)(n * 4 + kk) * 64 + lane) * 8);
#pragma unroll
        for (int kk = 0; kk < 4; ++kk) {
            acc[n][0] = __builtin_amdgcn_mfma_f32_16x16x32_f16(a[0][kk], b[kk], acc[n][0], 0, 0, 0);
            acc[n][1] = __builtin_amdgcn_mfma_f32_16x16x32_f16(a[1][kk], b[kk], acc[n][1], 0, 0, 0);
        }
    }

    // epilogue: C/D layout (HW-verified): row = 4g + i, col = 16n + cc.
    // Pack col pairs via shfl_xor(1); even-cc lanes store half2.
#pragma unroll
    for (int m = 0; m < 2; ++m)
#pragma unroll
        for (int i = 0; i < 4; ++i) {
            int r = row0 + 32 * w + 16 * m + 4 * g + i;
            bool ok = (r < M) && !(cc & 1);
#pragma unroll
            for (int n = 0; n < 16; ++n) {
                float v0 = acc[n][m][i];
                float v1 = __shfl_xor(v0, 1);
                if (ok) {
                    half2v h2; h2.x = (_Float16)v0; h2.y = (_Float16)v1;
                    *(half2v*)(h1h + (size_t)r * 256 + n * 16 + cc) = h2;
                }
            }
        }
}

// ---------------- per-node attention coefficients, fp16 h (layer 1) ----------------

__global__ __launch_bounds__(256)
void alpha1h_kernel(const _Float16* __restrict__ h, const float* __restrict__ a_src,
                    const float* __restrict__ a_dst, float* __restrict__ as,
                    float* __restrict__ ad) {
    int n = (blockIdx.x * 256 + threadIdx.x) >> 6;
    if (n >= NN) return;
    int lane = threadIdx.x & 63;
    int hd = lane >> 4, q = lane & 15;
    half4v v = *(const half4v*)(h + (size_t)n * 256 + hd * 64 + q * 4);
    float4 cs = *(const float4*)(a_src + hd * 64 + q * 4);
    float4 cd = *(const float4*)(a_dst + hd * 64 + q * 4);
    float ss = (float)v.x * cs.x + (float)v.y * cs.y + (float)v.z * cs.z + (float)v.w * cs.w;
    float sd = (float)v.x * cd.x + (float)v.y * cd.y + (float)v.z * cd.z + (float)v.w * cd.w;
#pragma unroll
    for (int m = 8; m >= 1; m >>= 1) {
        ss += __shfl_xor(ss, m);
        sd += __shfl_xor(sd, m);
    }
    if (q == 0) { as[n * 4 + hd] = ss; ad[n * 4 + hd] = sd; }
}

// ---------------- layer-2 GEMM (f32 vector): f32 + fp16 dual store ----------------

template<int K, int BK, int BN, int TN>
__global__ __launch_bounds__(256)
void gemm2_kernel(const float* __restrict__ A, const float* __restrict__ B,
                  float* __restrict__ C, _Float16* __restrict__ Ch,
                  int M, int Nfull) {
    constexpr int BM  = 64;
    constexpr int LDA = BK + 4;
    __shared__ float As[BM * LDA];
    __shared__ float Bs[BK * BN];
    const int tid  = threadIdx.x;
    const int row0 = blockIdx.x * BM;
    const int col0 = blockIdx.y * BN;
    const int tx   = tid & 15;
    const int ty   = tid >> 4;

    float acc[4][TN];
#pragma unroll
    for (int i = 0; i < 4; ++i)
#pragma unroll
        for (int j = 0; j < TN; ++j) acc[i][j] = 0.f;

    for (int kt = 0; kt < K; kt += BK) {
        constexpr int AV = (BM * BK) / (256 * 4);
#pragma unroll
        for (int v = 0; v < AV; ++v) {
            int idx = (v * 256 + tid) * 4;
            int r = idx / BK, k = idx % BK;
            int rg = row0 + r; if (rg >= M) rg = M - 1;
            *(float4*)(As + r * LDA + k) = *(const float4*)(A + (size_t)rg * K + kt + k);
        }
        constexpr int BV = (BK * BN) / (256 * 4);
#pragma unroll
        for (int v = 0; v < BV; ++v) {
            int idx = (v * 256 + tid) * 4;
            int k = idx / BN, c = idx % BN;
            *(float4*)(Bs + k * BN + c) = *(const float4*)(B + (size_t)(kt + k) * Nfull + col0 + c);
        }
        __syncthreads();

#pragma unroll
        for (int k = 0; k < BK; k += 4) {
            float4 a[4];
#pragma unroll
            for (int i = 0; i < 4; ++i)
                a[i] = *(const float4*)(As + (ty * 4 + i) * LDA + k);
#pragma unroll
            for (int kk = 0; kk < 4; ++kk) {
                float b[TN];
                float2 tv = *(const float2*)(Bs + (k + kk) * BN + tx * 2);
                b[0] = tv.x; b[1] = tv.y;
#pragma unroll
                for (int i = 0; i < 4; ++i) {
                    float av = (kk == 0) ? a[i].x : (kk == 1) ? a[i].y
                             : (kk == 2) ? a[i].z : a[i].w;
#pragma unroll
                    for (int j = 0; j < TN; ++j)
                        acc[i][j] = fmaf(av, b[j], acc[i][j]);
                }
            }
        }
        __syncthreads();
    }

#pragma unroll
    for (int i = 0; i < 4; ++i) {
        int r = row0 + ty * 4 + i;
        if (r < M) {
            float2 o; o.x = acc[i][0]; o.y = acc[i][1];
            *(float2*)(C + (size_t)r * Nfull + col0 + tx * 2) = o;
            half2v oh; oh.x = (_Float16)acc[i][0]; oh.y = (_Float16)acc[i][1];
            *(half2v*)(Ch + (size_t)r * Nfull + col0 + tx * 2) = oh;
        }
    }
}

// ---------------- per-node attention coefficients (layer 2, f32 h) ----------------

template<int C>
__global__ __launch_bounds__(256)
void alpha_kernel(const float* __restrict__ h, const float* __restrict__ a_src,
                  const float* __restrict__ a_dst, float* __restrict__ as,
                  float* __restrict__ ad) {
    int n = (blockIdx.x * 256 + threadIdx.x) >> 6;
    if (n >= NN) return;
    int lane = threadIdx.x & 63;
    int hd = lane >> 4, q = lane & 15;
    float ss = 0.f, sd = 0.f;
    for (int c = q; c < C; c += 16) {
        float v = h[(size_t)n * (4 * C) + hd * C + c];
        ss = fmaf(v, a_src[hd * C + c], ss);
        sd = fmaf(v, a_dst[hd * C + c], sd);
    }
#pragma unroll
    for (int m = 8; m >= 1; m >>= 1) {
        ss += __shfl_xor(ss, m);
        sd += __shfl_xor(sd, m);
    }
    if (q == 0) { as[n * 4 + hd] = ss; ad[n * 4 + hd] = sd; }
}

// ---------------- layer-1 edge softmax + aggregation (fp16 gather) ----------------

__global__ __launch_bounds__(256)
void agg1_kernel(const _Float16* __restrict__ h1h, const float* __restrict__ as1,
                 const float* __restrict__ ad1, const int* __restrict__ off,
                 const int* __restrict__ csr, const float* __restrict__ b1,
                 float* __restrict__ h1o) {
    int n = (blockIdx.x * 256 + threadIdx.x) >> 6;
    if (n >= NN) return;
    int lane = threadIdx.x & 63;
    int hd = lane >> 4, q = lane & 15;
    float adv = ad1[n * 4 + hd];
    int e0 = off[n], e1 = off[n + 1];
    float a0 = 0.f, a1 = 0.f, a2 = 0.f, a3 = 0.f, den = 0.f;
    int j = e0;
    for (; j + 4 <= e1; j += 4) {
        int s0 = csr[j], s1 = csr[j + 1], s2 = csr[j + 2], s3 = csr[j + 3];
        half4v v0 = *(const half4v*)(h1h + (size_t)s0 * 256 + lane * 4);
        half4v v1 = *(const half4v*)(h1h + (size_t)s1 * 256 + lane * 4);
        half4v v2 = *(const half4v*)(h1h + (size_t)s2 * 256 + lane * 4);
        half4v v3 = *(const half4v*)(h1h + (size_t)s3 * 256 + lane * 4);
        float w0 = lrelu_exp(as1[s0 * 4 + hd] + adv);
        float w1 = lrelu_exp(as1[s1 * 4 + hd] + adv);
        float w2 = lrelu_exp(as1[s2 * 4 + hd] + adv);
        float w3 = lrelu_exp(as1[s3 * 4 + hd] + adv);
        den += (w0 + w1) + (w2 + w3);
        a0 = fmaf(w0, (float)v0.x, a0); a1 = fmaf(w0, (float)v0.y, a1);
        a2 = fmaf(w0, (float)v0.z, a2); a3 = fmaf(w0, (float)v0.w, a3);
        a0 = fmaf(w1, (float)v1.x, a0); a1 = fmaf(w1, (float)v1.y, a1);
        a2 = fmaf(w1, (float)v1.z, a2); a3 = fmaf(w1, (float)v1.w, a3);
        a0 = fmaf(w2, (float)v2.x, a0); a1 = fmaf(w2, (float)v2.y, a1);
        a2 = fmaf(w2, (float)v2.z, a2); a3 = fmaf(w2, (float)v2.w, a3);
        a0 = fmaf(w3, (float)v3.x, a0); a1 = fmaf(w3, (float)v3.y, a1);
        a2 = fmaf(w3, (float)v3.z, a2); a3 = fmaf(w3, (float)v3.w, a3);
    }
    for (; j < e1; ++j) {
        int s = csr[j];
        float w = lrelu_exp(as1[s * 4 + hd] + adv);
        den += w;
        half4v hv = *(const half4v*)(h1h + (size_t)s * 256 + lane * 4);
        a0 = fmaf(w, (float)hv.x, a0); a1 = fmaf(w, (float)hv.y, a1);
        a2 = fmaf(w, (float)hv.z, a2); a3 = fmaf(w, (float)hv.w, a3);
    }
    float inv = 1.f / (den + 1e-16f);
    a0 *= inv; a1 *= inv; a2 *= inv; a3 *= inv;
    a0 += __shfl_xor(a0, 16); a0 += __shfl_xor(a0, 32);
    a1 += __shfl_xor(a1, 16); a1 += __shfl_xor(a1, 32);
    a2 += __shfl_xor(a2, 16); a2 += __shfl_xor(a2, 32);
    a3 += __shfl_xor(a3, 16); a3 += __shfl_xor(a3, 32);
    if (hd == 0) {
        int c = q * 4;
        float4 o;
        o.x = fmaxf(a0 * 0.25f + b1[c + 0], 0.f);
        o.y = fmaxf(a1 * 0.25f + b1[c + 1], 0.f);
        o.z = fmaxf(a2 * 0.25f + b1[c + 2], 0.f);
        o.w = fmaxf(a3 * 0.25f + b1[c + 3], 0.f);
        *(float4*)(h1o + (size_t)n * 64 + c) = o;
    }
}

// ---------------- layer-2 edge softmax + aggregation (fp16 gather) ----------------

__global__ __launch_bounds__(256)
void agg2_kernel(const _Float16* __restrict__ h2h, const float* __restrict__ as2,
                 const float* __restrict__ ad2, const int* __restrict__ off,
                 const int* __restrict__ csr, const float* __restrict__ b2,
                 float* __restrict__ out) {
    int n = (blockIdx.x * 256 + threadIdx.x) >> 6;
    if (n >= NN) return;
    int lane = threadIdx.x & 63;
    int hd = lane >> 4, q = lane & 15;
    float adv = ad2[n * 4 + hd];
    int e0 = off[n], e1 = off[n + 1];
    float a0 = 0.f, a1 = 0.f, a2 = 0.f, den = 0.f;
    int j = e0;
    for (; j + 4 <= e1; j += 4) {
        int s0 = csr[j], s1 = csr[j + 1], s2 = csr[j + 2], s3 = csr[j + 3];
        const _Float16* r0 = h2h + (size_t)s0 * 160 + hd * 40;
        const _Float16* r1 = h2h + (size_t)s1 * 160 + hd * 40;
        const _Float16* r2 = h2h + (size_t)s2 * 160 + hd * 40;
        const _Float16* r3 = h2h + (size_t)s3 * 160 + hd * 40;
        half2v u0 = *(const half2v*)(r0 + q * 2);
        half2v u1 = *(const half2v*)(r1 + q * 2);
        half2v u2 = *(const half2v*)(r2 + q * 2);
        half2v u3 = *(const half2v*)(r3 + q * 2);
        float t0 = (q < 8) ? (float)r0[32 + q] : 0.f;
        float t1 = (q < 8) ? (float)r1[32 + q] : 0.f;
        float t2 = (q < 8) ? (float)r2[32 + q] : 0.f;
        float t3 = (q < 8) ? (float)r3[32 + q] : 0.f;
        float w0 = lrelu_exp(as2[s0 * 4 + hd] + adv);
        float w1 = lrelu_exp(as2[s1 * 4 + hd] + adv);
        float w2 = lrelu_exp(as2[s2 * 4 + hd] + adv);
        float w3 = lrelu_exp(as2[s3 * 4 + hd] + adv);
        den += (w0 + w1) + (w2 + w3);
        a0 = fmaf(w0, (float)u0.x, a0); a1 = fmaf(w0, (float)u0.y, a1); a2 = fmaf(w0, t0, a2);
        a0 = fmaf(w1, (float)u1.x, a0); a1 = fmaf(w1, (float)u1.y, a1); a2 = fmaf(w1, t1, a2);
        a0 = fmaf(w2, (float)u2.x, a0); a1 = fmaf(w2, (float)u2.y, a1); a2 = fmaf(w2, t2, a2);
        a0 = fmaf(w3, (float)u3.x, a0); a1 = fmaf(w3, (float)u3.y, a1); a2 = fmaf(w3, t3, a2);
    }
    for (; j < e1; ++j) {
        int s = csr[j];
        float w = lrelu_exp(as2[s * 4 + hd] + adv);
        den += w;
        const _Float16* hr = h2h + (size_t)s * 160 + hd * 40;
        half2v hv = *(const half2v*)(hr + q * 2);
        a0 = fmaf(w, (float)hv.x, a0);
        a1 = fmaf(w, (float)hv.y, a1);
        float h2v = (q < 8) ? (float)hr[32 + q] : 0.f;
        a2 = fmaf(w, h2v, a2);
    }
    float inv = 1.f / (den + 1e-16f);
    a0 *= inv; a1 *= inv; a2 *= inv;
    a0 += __shfl_xor(a0, 16); a0 += __shfl_xor(a0, 32);
    a1 += __shfl_xor(a1, 16); a1 += __shfl_xor(a1, 32);
    a2 += __shfl_xor(a2, 16); a2 += __shfl_xor(a2, 32);
    if (hd == 0) {
        float2 o;
        o.x = a0 * 0.25f + b2[q * 2 + 0];
        o.y = a1 * 0.25f + b2[q * 2 + 1];
        *(float2*)(out + (size_t)n * 40 + q * 2) = o;
        if (q < 8) out[(size_t)n * 40 + 32 + q] = a2 * 0.25f + b2[32 + q];
    }
}

// ---------------- launch ----------------

extern "C" void kernel_launch(void* const* d_in, const int* in_sizes, int n_in,
                              void* d_out, int out_size, void* d_ws, size_t ws_size,
                              hipStream_t stream) {
    const float* x      = (const float*)d_in[0];
    const int*   ei     = (const int*)  d_in[1];   // [2][E], int32 per harness
    const float* W1     = (const float*)d_in[2];
    const float* a_src1 = (const float*)d_in[3];
    const float* a_dst1 = (const float*)d_in[4];
    const float* b1     = (const float*)d_in[5];
    const float* W2     = (const float*)d_in[6];
    const float* a_src2 = (const float*)d_in[7];
    const float* a_dst2 = (const float*)d_in[8];
    const float* b2     = (const float*)d_in[9];
    float* out = (float*)d_out;

    char* p = (char*)d_ws;
    auto alloc = [&](size_t bytes) {
        void* r = (void*)p;
        p += (bytes + 255) & ~(size_t)255;
        return r;
    };
    int*       deg  = (int*)alloc((size_t)NN * 4);
    int*       off  = (int*)alloc((size_t)(NN + 1) * 4);
    int*       cur  = (int*)alloc((size_t)NN * 4);
    int*       bsum = (int*)alloc((size_t)NB_SCAN * 4);
    int*       csr  = (int*)alloc((size_t)EP * 4);
    _Float16*  W1p  = (_Float16*)alloc((size_t)128 * 256 * 2);  // fragment-packed W1
    _Float16*  h1h  = (_Float16*)alloc((size_t)NN * 256 * 2);   // fp16 gather table L1
    float*     as1  = (float*)alloc((size_t)NN * 4 * 4);
    float*     ad1  = (float*)alloc((size_t)NN * 4 * 4);
    float*     h1o  = (float*)alloc((size_t)NN * 64 * 4);
    float*     h2   = (float*)alloc((size_t)NN * 160 * 4);      // f32 for alpha2
    _Float16*  h2h  = (_Float16*)alloc((size_t)NN * 160 * 2);   // fp16 gather table L2
    float*     as2  = (float*)alloc((size_t)NN * 4 * 4);
    float*     ad2  = (float*)alloc((size_t)NN * 4 * 4);

    // CSR over dst (shared by both layers)
    init_deg<<<(NN + 255) / 256, 256, 0, stream>>>(deg);
    hist_kernel<<<(EE + 255) / 256, 256, 0, stream>>>(ei, deg);
    scan_blocks<<<NB_SCAN, 256, 0, stream>>>(deg, off, bsum);
    scan_spine<<<1, 64, 0, stream>>>(bsum, off);
    scan_apply<<<NB_SCAN, 256, 0, stream>>>(bsum, off, cur);
    scatter_kernel<<<(EP + 255) / 256, 256, 0, stream>>>(ei, cur, csr);

    // layer 1 (MFMA GEMM, fp16 h table, separate fp16 alpha pass)
    prep_w1<<<16, 256, 0, stream>>>(W1, W1p);
    gemm1_mfma<<<(NN + 127) / 128, 256, 0, stream>>>(x, W1p, h1h, NN);
    alpha1h_kernel<<<(NN + 3) / 4, 256, 0, stream>>>(h1h, a_src1, a_dst1, as1, ad1);
    agg1_kernel<<<(NN + 3) / 4, 256, 0, stream>>>(h1h, as1, ad1, off, csr, b1, h1o);

    // layer 2
    dim3 g2((NN + 63) / 64, 160 / 32);
    gemm2_kernel<64, 64, 32, 2><<<g2, 256, 0, stream>>>(h1o, W2, h2, h2h, NN, 160);
    alpha_kernel<40><<<(NN + 3) / 4, 256, 0, stream>>>(h2, a_src2, a_dst2, as2, ad2);
    agg2_kernel<<<(NN + 3) / 4, 256, 0, stream>>>(h2h, as2, ad2, off, csr, b2, out);
}

// Round 10
// 272.473 us; speedup vs baseline: 1.2524x; 1.2524x over previous
//
#include <hip/hip_runtime.h>
#include <hip/hip_bf16.h>

// Problem constants (from reference)
#define NN      50000
#define EE      800000
#define EP      (EE + NN)      // edges + self loops
#define F_IN    128
#define HID     64
#define HEADS   4
#define NCLS    40
#define SLOPE   0.2f

#define NB_SCAN ((NN + 1023) / 1024)   // 49 blocks of 1024 elements

typedef _Float16 half8v __attribute__((ext_vector_type(8)));
typedef _Float16 half4v __attribute__((ext_vector_type(4)));
typedef _Float16 half2v __attribute__((ext_vector_type(2)));
typedef float    f32x4  __attribute__((ext_vector_type(4)));

__device__ __forceinline__ float lrelu_exp(float e) {
    e = (e > 0.f) ? e : SLOPE * e;
    return __expf(e);
}

// ---------------- CSR build ----------------

__global__ __launch_bounds__(256) void init_deg(int* deg) {
    int i = blockIdx.x * 256 + threadIdx.x;
    if (i < NN) deg[i] = 1;   // self-loop
}

__global__ __launch_bounds__(256) void hist_kernel(const int* __restrict__ ei, int* deg) {
    int e = blockIdx.x * 256 + threadIdx.x;
    if (e < EE) atomicAdd(&deg[ei[EE + e]], 1);   // dst = ei[1][e]
}

// ---- multi-block exclusive scan over NN degrees (3 passes, all parallel) ----
__global__ __launch_bounds__(256) void scan_blocks(const int* __restrict__ deg,
                                                   int* __restrict__ off,
                                                   int* __restrict__ bsum) {
    __shared__ int wsum[4];
    const int bid = blockIdx.x, t = threadIdx.x;
    const int base = bid * 1024 + t * 4;
    int d0 = 0, d1 = 0, d2 = 0, d3 = 0;
    if (base + 3 < NN) {
        int4 v = *(const int4*)(deg + base);
        d0 = v.x; d1 = v.y; d2 = v.z; d3 = v.w;
    } else {
        if (base + 0 < NN) d0 = deg[base + 0];
        if (base + 1 < NN) d1 = deg[base + 1];
        if (base + 2 < NN) d2 = deg[base + 2];
        if (base + 3 < NN) d3 = deg[base + 3];
    }
    const int tsum = d0 + d1 + d2 + d3;
    const int lane = t & 63, wv = t >> 6;
    int inc = tsum;
#pragma unroll
    for (int o = 1; o < 64; o <<= 1) {
        int u = __shfl_up(inc, o);
        if (lane >= o) inc += u;
    }
    if (lane == 63) wsum[wv] = inc;
    __syncthreads();
    int woff = 0;
#pragma unroll
    for (int w = 0; w < 4; ++w) woff += (w < wv) ? wsum[w] : 0;
    const int excl = woff + inc - tsum;
    if (base + 3 < NN) {
        int4 o4;
        o4.x = excl;
        o4.y = excl + d0;
        o4.z = excl + d0 + d1;
        o4.w = excl + d0 + d1 + d2;
        *(int4*)(off + base) = o4;
    } else {
        if (base + 0 < NN) off[base + 0] = excl;
        if (base + 1 < NN) off[base + 1] = excl + d0;
        if (base + 2 < NN) off[base + 2] = excl + d0 + d1;
        if (base + 3 < NN) off[base + 3] = excl + d0 + d1 + d2;
    }
    if (t == 255) bsum[bid] = woff + inc;   // block total
}

__global__ __launch_bounds__(64) void scan_spine(int* __restrict__ bsum,
                                                 int* __restrict__ off) {
    const int lane = threadIdx.x;
    int v = (lane < NB_SCAN) ? bsum[lane] : 0;
    int inc = v;
#pragma unroll
    for (int o = 1; o < 64; o <<= 1) {
        int u = __shfl_up(inc, o);
        if (lane >= o) inc += u;
    }
    if (lane < NB_SCAN) bsum[lane] = inc - v;   // exclusive prefix
    if (lane == 63) off[NN] = inc;              // grand total == EP
}

__global__ __launch_bounds__(256) void scan_apply(const int* __restrict__ bsum,
                                                  int* __restrict__ off,
                                                  int* __restrict__ cur) {
    const int bid = blockIdx.x, t = threadIdx.x;
    const int boff = bsum[bid];
    const int base = bid * 1024 + t * 4;
    if (base + 3 < NN) {
        int4 v = *(const int4*)(off + base);
        v.x += boff; v.y += boff; v.z += boff; v.w += boff;
        *(int4*)(off + base) = v;
        *(int4*)(cur + base) = v;
    } else {
        for (int i = 0; i < 4; ++i)
            if (base + i < NN) {
                int v = off[base + i] + boff;
                off[base + i] = v;
                cur[base + i] = v;
            }
    }
}

__global__ __launch_bounds__(256) void scatter_kernel(const int* __restrict__ ei,
                                                      int* __restrict__ cur,
                                                      int* __restrict__ csr) {
    int i = blockIdx.x * 256 + threadIdx.x;
    if (i >= EP) return;
    int s, d;
    if (i < NN) { s = i; d = i; }           // self loop
    else { int e = i - NN; s = ei[e]; d = ei[EE + e]; }
    int pos = atomicAdd(&cur[d], 1);
    csr[pos] = s;
}

// ---------------- W1 -> fragment-packed fp16 table (once per launch) ----------------
// sigma(g,j) = 8g+j applied identically to A and B fragments (K-perm invariance).
__global__ __launch_bounds__(256) void prep_w1(const float* __restrict__ W1,
                                               _Float16* __restrict__ W1p) {
    int idx = blockIdx.x * 256 + threadIdx.x;   // 16*4*64 = 4096 fragments-of-8
    if (idx >= 16 * 4 * 64) return;
    int l = idx & 63, kk = (idx >> 6) & 3, f = idx >> 8;
    int k0 = 32 * kk + 8 * (l >> 4);
    int c  = 16 * f + (l & 15);
    half8v v;
#pragma unroll
    for (int j = 0; j < 8; ++j) v[j] = (_Float16)W1[(size_t)(k0 + j) * 256 + c];
    *(half8v*)(W1p + (size_t)idx * 8) = v;
}

// ---- layer-2 folded logit vectors: vs[h][k] = sum_c W2[k, h*40+c] * a_src2[h][c] ----
__global__ __launch_bounds__(256) void prep_v(const float* __restrict__ W2,
                                              const float* __restrict__ a_src2,
                                              const float* __restrict__ a_dst2,
                                              float* __restrict__ vs,
                                              float* __restrict__ vd) {
    int idx = threadIdx.x;              // 4 heads x 64 k
    int h = idx >> 6, k = idx & 63;
    float s = 0.f, d = 0.f;
    for (int c = 0; c < NCLS; ++c) {
        float w = W2[(size_t)k * 160 + h * 40 + c];
        s = fmaf(w, a_src2[h * 40 + c], s);
        d = fmaf(w, a_dst2[h * 40 + c], d);
    }
    vs[idx] = s; vd[idx] = d;
}

// ---- W2 -> fragment-packed fp16 for gemm_out: B[kappa][c], kappa=(h*64+kx), 48 cols pad ----
__global__ __launch_bounds__(256) void prep_w2(const float* __restrict__ W2,
                                               _Float16* __restrict__ Bp) {
    int idx = blockIdx.x * 256 + threadIdx.x;   // 3*8*64 = 1536 fragments-of-8
    if (idx >= 1536) return;
    int l = idx & 63, kk = (idx >> 6) & 7, n = idx >> 9;
    int c = 16 * n + (l & 15);
    half8v v;
#pragma unroll
    for (int j = 0; j < 8; ++j) {
        int kap = 32 * kk + 8 * (l >> 4) + j;   // kappa in [0,256)
        float w = (c < NCLS) ? W2[(size_t)(kap & 63) * 160 + (kap >> 6) * 40 + c] : 0.f;
        v[j] = (_Float16)w;
    }
    *(half8v*)(Bp + (size_t)idx * 8) = v;
}

// ---------------- layer-1 GEMM via f16 MFMA (unchanged from R9) ----------------
__global__ __launch_bounds__(256)
void gemm1_mfma(const float* __restrict__ A, const _Float16* __restrict__ W1p,
                _Float16* __restrict__ h1h, int M) {
    __shared__ _Float16 Al[128 * 128];   // 32 KB
    const int t    = threadIdx.x;
    const int row0 = blockIdx.x * 128;

#pragma unroll
    for (int i = 0; i < 16; ++i) {
        int flat = i * 1024 + t * 4;
        int r = flat >> 7, c = flat & 127;
        int rg = row0 + r; if (rg >= M) rg = M - 1;
        float4 v = *(const float4*)(A + (size_t)rg * 128 + c);
        half4v hv;
        hv.x = (_Float16)v.x; hv.y = (_Float16)v.y;
        hv.z = (_Float16)v.z; hv.w = (_Float16)v.w;
        int byte = (r * 256 + c * 2) ^ ((r & 7) << 4);
        *(half4v*)((char*)Al + byte) = hv;
    }
    __syncthreads();

    const int lane = t & 63;
    const int w    = t >> 6;
    const int g    = lane >> 4, cc = lane & 15;

    half8v a[2][4];
#pragma unroll
    for (int m = 0; m < 2; ++m)
#pragma unroll
        for (int kk = 0; kk < 4; ++kk) {
            int r = 32 * w + 16 * m + cc;
            int byte = (r * 256 + (32 * kk + 8 * g) * 2) ^ ((r & 7) << 4);
            a[m][kk] = *(const half8v*)((const char*)Al + byte);
        }

    f32x4 acc[16][2];
#pragma unroll
    for (int n = 0; n < 16; ++n)
#pragma unroll
        for (int m = 0; m < 2; ++m)
#pragma unroll
            for (int i = 0; i < 4; ++i) acc[n][m][i] = 0.f;

#pragma unroll
    for (int n = 0; n < 16; ++n) {
        half8v b[4];
#pragma unroll
        for (int kk = 0; kk < 4; ++kk)
            b[kk] = *(const half8v*)(W1p + ((size_t)(n * 4 + kk) * 64 + lane) * 8);
#pragma unroll
        for (int kk = 0; kk < 4; ++kk) {
            acc[n][0] = __builtin_amdgcn_mfma_f32_16x16x32_f16(a[0][kk], b[kk], acc[n][0], 0, 0, 0);
            acc[n][1] = __builtin_amdgcn_mfma_f32_16x16x32_f16(a[1][kk], b[kk], acc[n][1], 0, 0, 0);
        }
    }

#pragma unroll
    for (int m = 0; m < 2; ++m)
#pragma unroll
        for (int i = 0; i < 4; ++i) {
            int r = row0 + 32 * w + 16 * m + 4 * g + i;
            bool ok = (r < M) && !(cc & 1);
#pragma unroll
            for (int n = 0; n < 16; ++n) {
                float v0 = acc[n][m][i];
                float v1 = __shfl_xor(v0, 1);
                if (ok) {
                    half2v h2; h2.x = (_Float16)v0; h2.y = (_Float16)v1;
                    *(half2v*)(h1h + (size_t)r * 256 + n * 16 + cc) = h2;
                }
            }
        }
}

// ---------------- per-node attention coefficients, fp16 h (layer 1) ----------------

__global__ __launch_bounds__(256)
void alpha1h_kernel(const _Float16* __restrict__ h, const float* __restrict__ a_src,
                    const float* __restrict__ a_dst, float* __restrict__ as,
                    float* __restrict__ ad) {
    int n = (blockIdx.x * 256 + threadIdx.x) >> 6;
    if (n >= NN) return;
    int lane = threadIdx.x & 63;
    int hd = lane >> 4, q = lane & 15;
    half4v v = *(const half4v*)(h + (size_t)n * 256 + hd * 64 + q * 4);
    float4 cs = *(const float4*)(a_src + hd * 64 + q * 4);
    float4 cd = *(const float4*)(a_dst + hd * 64 + q * 4);
    float ss = (float)v.x * cs.x + (float)v.y * cs.y + (float)v.z * cs.z + (float)v.w * cs.w;
    float sd = (float)v.x * cd.x + (float)v.y * cd.y + (float)v.z * cd.z + (float)v.w * cd.w;
#pragma unroll
    for (int m = 8; m >= 1; m >>= 1) {
        ss += __shfl_xor(ss, m);
        sd += __shfl_xor(sd, m);
    }
    if (q == 0) { as[n * 4 + hd] = ss; ad[n * 4 + hd] = sd; }
}

// ---------------- layer-1 edge softmax + aggregation ----------------
// Writes h1o as fp16 table only, and fuses layer-2 logits (exact f32, in-register).

__global__ __launch_bounds__(256)
void agg1_kernel(const _Float16* __restrict__ h1h, const float* __restrict__ as1,
                 const float* __restrict__ ad1, const int* __restrict__ off,
                 const int* __restrict__ csr, const float* __restrict__ b1,
                 const float* __restrict__ vs, const float* __restrict__ vd,
                 _Float16* __restrict__ h1of, float* __restrict__ as2,
                 float* __restrict__ ad2) {
    int n = (blockIdx.x * 256 + threadIdx.x) >> 6;
    if (n >= NN) return;
    int lane = threadIdx.x & 63;
    int hd = lane >> 4, q = lane & 15;
    float adv = ad1[n * 4 + hd];
    int e0 = off[n], e1 = off[n + 1];
    float a0 = 0.f, a1 = 0.f, a2 = 0.f, a3 = 0.f, den = 0.f;
    int j = e0;
    for (; j + 4 <= e1; j += 4) {
        int s0 = csr[j], s1 = csr[j + 1], s2 = csr[j + 2], s3 = csr[j + 3];
        half4v v0 = *(const half4v*)(h1h + (size_t)s0 * 256 + lane * 4);
        half4v v1 = *(const half4v*)(h1h + (size_t)s1 * 256 + lane * 4);
        half4v v2 = *(const half4v*)(h1h + (size_t)s2 * 256 + lane * 4);
        half4v v3 = *(const half4v*)(h1h + (size_t)s3 * 256 + lane * 4);
        float w0 = lrelu_exp(as1[s0 * 4 + hd] + adv);
        float w1 = lrelu_exp(as1[s1 * 4 + hd] + adv);
        float w2 = lrelu_exp(as1[s2 * 4 + hd] + adv);
        float w3 = lrelu_exp(as1[s3 * 4 + hd] + adv);
        den += (w0 + w1) + (w2 + w3);
        a0 = fmaf(w0, (float)v0.x, a0); a1 = fmaf(w0, (float)v0.y, a1);
        a2 = fmaf(w0, (float)v0.z, a2); a3 = fmaf(w0, (float)v0.w, a3);
        a0 = fmaf(w1, (float)v1.x, a0); a1 = fmaf(w1, (float)v1.y, a1);
        a2 = fmaf(w1, (float)v1.z, a2); a3 = fmaf(w1, (float)v1.w, a3);
        a0 = fmaf(w2, (float)v2.x, a0); a1 = fmaf(w2, (float)v2.y, a1);
        a2 = fmaf(w2, (float)v2.z, a2); a3 = fmaf(w2, (float)v2.w, a3);
        a0 = fmaf(w3, (float)v3.x, a0); a1 = fmaf(w3, (float)v3.y, a1);
        a2 = fmaf(w3, (float)v3.z, a2); a3 = fmaf(w3, (float)v3.w, a3);
    }
    for (; j < e1; ++j) {
        int s = csr[j];
        float w = lrelu_exp(as1[s * 4 + hd] + adv);
        den += w;
        half4v hv = *(const half4v*)(h1h + (size_t)s * 256 + lane * 4);
        a0 = fmaf(w, (float)hv.x, a0); a1 = fmaf(w, (float)hv.y, a1);
        a2 = fmaf(w, (float)hv.z, a2); a3 = fmaf(w, (float)hv.w, a3);
    }
    float inv = 1.f / (den + 1e-16f);
    a0 *= inv; a1 *= inv; a2 *= inv; a3 *= inv;
    a0 += __shfl_xor(a0, 16); a0 += __shfl_xor(a0, 32);
    a1 += __shfl_xor(a1, 16); a1 += __shfl_xor(a1, 32);
    a2 += __shfl_xor(a2, 16); a2 += __shfl_xor(a2, 32);
    a3 += __shfl_xor(a3, 16); a3 += __shfl_xor(a3, 32);
    if (hd == 0) {
        int c = q * 4;
        float o0 = fmaxf(a0 * 0.25f + b1[c + 0], 0.f);
        float o1 = fmaxf(a1 * 0.25f + b1[c + 1], 0.f);
        float o2 = fmaxf(a2 * 0.25f + b1[c + 2], 0.f);
        float o3 = fmaxf(a3 * 0.25f + b1[c + 3], 0.f);
        half4v hv;
        hv.x = (_Float16)o0; hv.y = (_Float16)o1;
        hv.z = (_Float16)o2; hv.w = (_Float16)o3;
        *(half4v*)(h1of + (size_t)n * 64 + c) = hv;
        // fused layer-2 logits: as2[n,h] = sum_k h1o[n,k] * vs[h][k]  (exact f32)
#pragma unroll
        for (int h = 0; h < 4; ++h) {
            float4 cs = *(const float4*)(vs + h * 64 + c);
            float4 cd = *(const float4*)(vd + h * 64 + c);
            float s = o0 * cs.x + o1 * cs.y + o2 * cs.z + o3 * cs.w;
            float d = o0 * cd.x + o1 * cd.y + o2 * cd.z + o3 * cd.w;
#pragma unroll
            for (int m = 1; m <= 8; m <<= 1) {
                s += __shfl_xor(s, m);
                d += __shfl_xor(d, m);
            }
            if (q == 0) { as2[n * 4 + h] = s; ad2[n * 4 + h] = d; }
        }
    }
}

// ---------------- layer-2 aggregation: gather RAW h1o (fp16), per-head accum ----------------
// lane (hd,q) accumulates g2[n][hd][q*4..q*4+3]; 128 B distinct gather per edge.

__global__ __launch_bounds__(256)
void agg2_kernel(const _Float16* __restrict__ h1of, const float* __restrict__ as2,
                 const float* __restrict__ ad2, const int* __restrict__ off,
                 const int* __restrict__ csr, _Float16* __restrict__ g2h) {
    int n = (blockIdx.x * 256 + threadIdx.x) >> 6;
    if (n >= NN) return;
    int lane = threadIdx.x & 63;
    int hd = lane >> 4, q = lane & 15;
    float adv = ad2[n * 4 + hd];
    int e0 = off[n], e1 = off[n + 1];
    float a0 = 0.f, a1 = 0.f, a2 = 0.f, a3 = 0.f, den = 0.f;
    int j = e0;
    for (; j + 4 <= e1; j += 4) {
        int s0 = csr[j], s1 = csr[j + 1], s2 = csr[j + 2], s3 = csr[j + 3];
        half4v v0 = *(const half4v*)(h1of + (size_t)s0 * 64 + q * 4);
        half4v v1 = *(const half4v*)(h1of + (size_t)s1 * 64 + q * 4);
        half4v v2 = *(const half4v*)(h1of + (size_t)s2 * 64 + q * 4);
        half4v v3 = *(const half4v*)(h1of + (size_t)s3 * 64 + q * 4);
        float w0 = lrelu_exp(as2[s0 * 4 + hd] + adv);
        float w1 = lrelu_exp(as2[s1 * 4 + hd] + adv);
        float w2 = lrelu_exp(as2[s2 * 4 + hd] + adv);
        float w3 = lrelu_exp(as2[s3 * 4 + hd] + adv);
        den += (w0 + w1) + (w2 + w3);
        a0 = fmaf(w0, (float)v0.x, a0); a1 = fmaf(w0, (float)v0.y, a1);
        a2 = fmaf(w0, (float)v0.z, a2); a3 = fmaf(w0, (float)v0.w, a3);
        a0 = fmaf(w1, (float)v1.x, a0); a1 = fmaf(w1, (float)v1.y, a1);
        a2 = fmaf(w1, (float)v1.z, a2); a3 = fmaf(w1, (float)v1.w, a3);
        a0 = fmaf(w2, (float)v2.x, a0); a1 = fmaf(w2, (float)v2.y, a1);
        a2 = fmaf(w2, (float)v2.z, a2); a3 = fmaf(w2, (float)v2.w, a3);
        a0 = fmaf(w3, (float)v3.x, a0); a1 = fmaf(w3, (float)v3.y, a1);
        a2 = fmaf(w3, (float)v3.z, a2); a3 = fmaf(w3, (float)v3.w, a3);
    }
    for (; j < e1; ++j) {
        int s = csr[j];
        float w = lrelu_exp(as2[s * 4 + hd] + adv);
        den += w;
        half4v hv = *(const half4v*)(h1of + (size_t)s * 64 + q * 4);
        a0 = fmaf(w, (float)hv.x, a0); a1 = fmaf(w, (float)hv.y, a1);
        a2 = fmaf(w, (float)hv.z, a2); a3 = fmaf(w, (float)hv.w, a3);
    }
    float inv = 1.f / (den + 1e-16f);
    half4v g;
    g.x = (_Float16)(a0 * inv); g.y = (_Float16)(a1 * inv);
    g.z = (_Float16)(a2 * inv); g.w = (_Float16)(a3 * inv);
    *(half4v*)(g2h + (size_t)n * 256 + hd * 64 + q * 4) = g;   // kappa = hd*64 + k
}

// ---------------- output GEMM via f16 MFMA: out[N,40] = 0.25 * g2[N,256] @ B + b2 ----------------

__global__ __launch_bounds__(256)
void gemm_out(const _Float16* __restrict__ g2h, const _Float16* __restrict__ Bp,
              const float* __restrict__ b2, float* __restrict__ out, int M) {
    __shared__ _Float16 Al[128 * 256];   // 64 KB
    const int t    = threadIdx.x;
    const int row0 = blockIdx.x * 128;

#pragma unroll
    for (int i = 0; i < 16; ++i) {
        int chunk = i * 256 + t;          // 4096 chunks of 8 halfs
        int r = chunk >> 5, c = (chunk & 31) * 8;
        int rg = row0 + r; if (rg >= M) rg = M - 1;
        half8v v = *(const half8v*)(g2h + (size_t)rg * 256 + c);
        int byte = (r * 512 + c * 2) ^ ((r & 7) << 4);
        *(half8v*)((char*)Al + byte) = v;
    }
    __syncthreads();

    const int lane = t & 63, w = t >> 6;
    const int g = lane >> 4, cc = lane & 15;

    half8v a[2][8];
#pragma unroll
    for (int m = 0; m < 2; ++m)
#pragma unroll
        for (int kk = 0; kk < 8; ++kk) {
            int r = 32 * w + 16 * m + cc;
            int byte = (r * 512 + (32 * kk + 8 * g) * 2) ^ ((r & 7) << 4);
            a[m][kk] = *(const half8v*)((const char*)Al + byte);
        }

    f32x4 acc[2][3];
#pragma unroll
    for (int m = 0; m < 2; ++m)
#pragma unroll
        for (int n = 0; n < 3; ++n)
#pragma unroll
            for (int i = 0; i < 4; ++i) acc[m][n][i] = 0.f;

#pragma unroll
    for (int n = 0; n < 3; ++n)
#pragma unroll
        for (int kk = 0; kk < 8; ++kk) {
            half8v b = *(const half8v*)(Bp + ((size_t)(n * 8 + kk) * 64 + lane) * 8);
            acc[0][n] = __builtin_amdgcn_mfma_f32_16x16x32_f16(a[0][kk], b, acc[0][n], 0, 0, 0);
            acc[1][n] = __builtin_amdgcn_mfma_f32_16x16x32_f16(a[1][kk], b, acc[1][n], 0, 0, 0);
        }

#pragma unroll
    for (int m = 0; m < 2; ++m)
#pragma unroll
        for (int i = 0; i < 4; ++i) {
            int r = row0 + 32 * w + 16 * m + 4 * g + i;
            if (r < M) {
#pragma unroll
                for (int n = 0; n < 3; ++n) {
                    int c = 16 * n + cc;
                    if (c < NCLS)
                        out[(size_t)r * 40 + c] = 0.25f * acc[m][n][i] + b2[c];
                }
            }
        }
}

// ---------------- launch ----------------

extern "C" void kernel_launch(void* const* d_in, const int* in_sizes, int n_in,
                              void* d_out, int out_size, void* d_ws, size_t ws_size,
                              hipStream_t stream) {
    const float* x      = (const float*)d_in[0];
    const int*   ei     = (const int*)  d_in[1];   // [2][E], int32 per harness
    const float* W1     = (const float*)d_in[2];
    const float* a_src1 = (const float*)d_in[3];
    const float* a_dst1 = (const float*)d_in[4];
    const float* b1     = (const float*)d_in[5];
    const float* W2     = (const float*)d_in[6];
    const float* a_src2 = (const float*)d_in[7];
    const float* a_dst2 = (const float*)d_in[8];
    const float* b2     = (const float*)d_in[9];
    float* out = (float*)d_out;

    char* p = (char*)d_ws;
    auto alloc = [&](size_t bytes) {
        void* r = (void*)p;
        p += (bytes + 255) & ~(size_t)255;
        return r;
    };
    int*       deg  = (int*)alloc((size_t)NN * 4);
    int*       off  = (int*)alloc((size_t)(NN + 1) * 4);
    int*       cur  = (int*)alloc((size_t)NN * 4);
    int*       bsum = (int*)alloc((size_t)NB_SCAN * 4);
    int*       csr  = (int*)alloc((size_t)EP * 4);
    _Float16*  W1p  = (_Float16*)alloc((size_t)128 * 256 * 2);  // fragment-packed W1
    _Float16*  Bp   = (_Float16*)alloc((size_t)1536 * 8 * 2);   // fragment-packed W2 (48 cols)
    float*     vs   = (float*)alloc((size_t)256 * 4);           // folded a_src2 (per head, 64-d)
    float*     vd   = (float*)alloc((size_t)256 * 4);
    _Float16*  h1h  = (_Float16*)alloc((size_t)NN * 256 * 2);   // fp16 gather table L1
    float*     as1  = (float*)alloc((size_t)NN * 4 * 4);
    float*     ad1  = (float*)alloc((size_t)NN * 4 * 4);
    _Float16*  h1of = (_Float16*)alloc((size_t)NN * 64 * 2);    // fp16 h1o gather table (6.4 MB)
    float*     as2  = (float*)alloc((size_t)NN * 4 * 4);
    float*     ad2  = (float*)alloc((size_t)NN * 4 * 4);
    _Float16*  g2h  = (_Float16*)alloc((size_t)NN * 256 * 2);   // aggregated per-head h1o

    // CSR over dst (shared by both layers)
    init_deg<<<(NN + 255) / 256, 256, 0, stream>>>(deg);
    hist_kernel<<<(EE + 255) / 256, 256, 0, stream>>>(ei, deg);
    scan_blocks<<<NB_SCAN, 256, 0, stream>>>(deg, off, bsum);
    scan_spine<<<1, 64, 0, stream>>>(bsum, off);
    scan_apply<<<NB_SCAN, 256, 0, stream>>>(bsum, off, cur);
    scatter_kernel<<<(EP + 255) / 256, 256, 0, stream>>>(ei, cur, csr);

    // weight prep (independent of CSR)
    prep_w1<<<16, 256, 0, stream>>>(W1, W1p);
    prep_v<<<1, 256, 0, stream>>>(W2, a_src2, a_dst2, vs, vd);
    prep_w2<<<6, 256, 0, stream>>>(W2, Bp);

    // layer 1
    gemm1_mfma<<<(NN + 127) / 128, 256, 0, stream>>>(x, W1p, h1h, NN);
    alpha1h_kernel<<<(NN + 3) / 4, 256, 0, stream>>>(h1h, a_src1, a_dst1, as1, ad1);
    agg1_kernel<<<(NN + 3) / 4, 256, 0, stream>>>(h1h, as1, ad1, off, csr, b1,
                                                  vs, vd, h1of, as2, ad2);

    // layer 2 (aggregate raw h1o per head, then one MFMA transform)
    agg2_kernel<<<(NN + 3) / 4, 256, 0, stream>>>(h1of, as2, ad2, off, csr, g2h);
    gemm_out<<<(NN + 127) / 128, 256, 0, stream>>>(g2h, Bp, b2, out, NN);
}